// Round 8
// baseline (134.837 us; speedup 1.0000x reference)
//
#include <hip/hip_runtime.h>

#define Bq 2
#define Lq 2048
#define Dq 1024
#define Hq 16
#define HDq 64

typedef _Float16 f16;
typedef _Float16 f16x8 __attribute__((ext_vector_type(8)));
typedef _Float16 f16x4 __attribute__((ext_vector_type(4)));
typedef __fp16 hf16x2 __attribute__((ext_vector_type(2)));
typedef float f32x4 __attribute__((ext_vector_type(4)));
typedef float f32x16 __attribute__((ext_vector_type(16)));

__device__ __forceinline__ void gload_lds16(const void* g, void* l) {
    __builtin_amdgcn_global_load_lds(
        (const __attribute__((address_space(1))) unsigned int*)g,
        (__attribute__((address_space(3))) unsigned int*)l, 16, 0, 0);
}

__device__ __forceinline__ void swap32(int& a, int& b) {
    asm volatile("v_permlane32_swap_b32 %0, %1" : "+v"(a), "+v"(b));
}

__device__ __forceinline__ int pk2(float a, float b) {
    hf16x2 v = __builtin_amdgcn_cvt_pkrtz(a, b);
    return __builtin_bit_cast(int, v);
}

// ---------------- fp32 -> fp16 conversion ------------------------------------
__global__ __launch_bounds__(256) void convert_kernel(
    const float* __restrict__ x,
    const float* __restrict__ wq, const float* __restrict__ wk, const float* __restrict__ wv,
    f16* __restrict__ x_h, f16* __restrict__ wq_h, f16* __restrict__ wk_h, f16* __restrict__ wv_h)
{
    const int NX = Bq*Lq*Dq;
    const int NW = Dq*Dq;
    const int total4 = (NX + 3*NW) / 4;
    for (int i = blockIdx.x*blockDim.x + threadIdx.x; i < total4;
         i += gridDim.x*blockDim.x) {
        int e = i * 4;
        const float* src; f16* dst; int off;
        if (e < NX) { src = x; dst = x_h; off = e; }
        else {
            int t = e - NX; int w = t >> 20; off = t & (NW-1);
            src = (w==0) ? wq : (w==1) ? wk : wv;
            dst = (w==0) ? wq_h : (w==1) ? wk_h : wv_h;
        }
        float4 v = *reinterpret_cast<const float4*>(src + off);
        f16x4 hv; hv.x=(f16)v.x; hv.y=(f16)v.y; hv.z=(f16)v.z; hv.w=(f16)v.w;
        *reinterpret_cast<f16x4*>(dst + off) = hv;
    }
}

// ---------------- QKV projection, fp16 MFMA ----------------------------------
#define GBM 128
#define GBN 128
#define GBK 32

__global__ __launch_bounds__(256) void qkv_mfma_kernel(
    const f16* __restrict__ x_h,
    const f16* __restrict__ wq_h, const f16* __restrict__ wk_h, const f16* __restrict__ wv_h,
    f16* __restrict__ q_h, f16* __restrict__ k_h, f16* __restrict__ vT_h)
{
    __shared__ __align__(16) f16 As[GBM*GBK];
    __shared__ __align__(16) f16 Bs[GBN*GBK];

    const int tid  = threadIdx.x;
    const int lane = tid & 63;
    const int wave = tid >> 6;
    const int wr = wave >> 1, wc = wave & 1;
    const int l15 = lane & 15, l4 = lane >> 4;
    const int n0 = blockIdx.x * GBN;
    const int m0 = blockIdx.y * GBM;
    const int z  = blockIdx.z;
    const f16* W = (z==0) ? wq_h : (z==1) ? wk_h : wv_h;

    const int sslot = tid & 3;

    f32x4 acc[4][4];
    #pragma unroll
    for (int i=0;i<4;++i)
        #pragma unroll
        for (int j=0;j<4;++j) acc[i][j] = f32x4{0.f,0.f,0.f,0.f};

    for (int kt = 0; kt < Dq; kt += GBK) {
        __syncthreads();
        #pragma unroll
        for (int j = 0; j < 2; ++j) {
            int slotIdx = tid + j*256;
            int row = slotIdx >> 2;
            gload_lds16(x_h + (size_t)(m0+row)*Dq + kt + sslot*8,
                        (char*)As + slotIdx*16);
            gload_lds16(W   + (size_t)(n0+row)*Dq + kt + sslot*8,
                        (char*)Bs + slotIdx*16);
        }
        __syncthreads();

        f16x8 a[4], b[4];
        #pragma unroll
        for (int m=0;m<4;++m) {
            int row = wr*64 + m*16 + l15;
            a[m] = *reinterpret_cast<const f16x8*>((const char*)As + row*64 + l4*16);
        }
        #pragma unroll
        for (int n=0;n<4;++n) {
            int row = wc*64 + n*16 + l15;
            b[n] = *reinterpret_cast<const f16x8*>((const char*)Bs + row*64 + l4*16);
        }
        #pragma unroll
        for (int m=0;m<4;++m)
            #pragma unroll
            for (int n=0;n<4;++n)
                acc[m][n] = __builtin_amdgcn_mfma_f32_16x16x32_f16(a[m], b[n], acc[m][n], 0,0,0);
    }

    #pragma unroll
    for (int m=0;m<4;++m) {
        #pragma unroll
        for (int r=0;r<4;++r) {
            int grow = m0 + wr*64 + m*16 + l4*4 + r;
            int b_   = grow >> 11;
            int lrow = grow & (Lq-1);
            #pragma unroll
            for (int n=0;n<4;++n) {
                int gcol = n0 + wc*64 + n*16 + l15;
                int h = gcol >> 6, d = gcol & 63;
                int bh = b_*Hq + h;
                f16 val = (f16)acc[m][n][r];
                if (z==0)      q_h[((size_t)bh*Lq + lrow)*HDq + d] = val;
                else if (z==1) k_h[((size_t)bh*Lq + lrow)*HDq + d] = val;
                else           vT_h[((size_t)bh*HDq + d)*Lq + lrow] = val;
            }
        }
    }
}

// ---------------- quantum -> 8x, f32, MFMA-C-fragment order ------------------
// per (b, t=key-tile, qt=32-row group): 2048 floats; element (kt,j,lane,c) =
// 8*quantum[b][qt*32+(lane&31)][t*64 + kt*32 + 8j + 4*(lane>>5) + c]
__global__ __launch_bounds__(256) void qm_pre_kernel(
    const float* __restrict__ quantum, float* __restrict__ qm_pre)
{
    __shared__ float qs[32][65];
    const int tid = threadIdx.x;
    const int qt = blockIdx.x, t = blockIdx.y, b = blockIdx.z;
    const float* base = quantum + ((size_t)b*Lq + qt*32)*Lq + t*64;
    #pragma unroll
    for (int i=0;i<2;++i) {
        int idx = tid + i*256;
        int r = idx >> 4, c = (idx & 15)*4;
        float4 v = *reinterpret_cast<const float4*>(base + (size_t)r*Lq + c);
        qs[r][c+0]=v.x*8.f; qs[r][c+1]=v.y*8.f; qs[r][c+2]=v.z*8.f; qs[r][c+3]=v.w*8.f;
    }
    __syncthreads();
    float* outb = qm_pre + (((size_t)b*32 + t)*64 + qt)*2048;
    #pragma unroll
    for (int i=0;i<2;++i) {
        int g = tid + i*256;            // 0..511
        int kt = g >> 8;
        int j  = (g >> 6) & 3;
        int lane = g & 63;
        int l31 = lane & 31, hi = lane >> 5;
        int col = kt*32 + 8*j + 4*hi;
        float4 v = { qs[l31][col], qs[l31][col+1], qs[l31][col+2], qs[l31][col+3] };
        *reinterpret_cast<float4*>(outb + ((size_t)kt*4 + j)*256 + lane*4) = v;
    }
}

// ---------------- flash attention: bias via MFMA accumulator init ------------
__global__ __launch_bounds__(256, 2) void attn4_kernel(
    const f16* __restrict__ q_h, const f16* __restrict__ k_h, const f16* __restrict__ vT_h,
    const float* __restrict__ qm_pre, const float* __restrict__ scale,
    float* __restrict__ out)
{
    __shared__ __align__(16) char lds[49152];   // 3 bufs x [K 8KB | V 8KB]

    const int tid  = threadIdx.x;
    const int lane = tid & 63;
    const int wave = tid >> 6;          // 0..3
    const int l31  = lane & 31;
    const int hi   = lane >> 5;
    const int bh = blockIdx.x;
    const int qb = blockIdx.y;
    const int b_ = bh >> 4, h = bh & 15;
    const int qW = qb*128 + wave*32;    // this wave's 32 q-rows
    const int qt = qb*4 + wave;         // 32-row tile index
    const float c1 = 0.125f * scale[h] * 1.44269504f;   // logits -> base-2
    const bool pos = (c1 >= 0.f);

    const f16* kbase = k_h  + (size_t)bh*Lq*HDq;
    const f16* vbase = vT_h + (size_t)bh*HDq*Lq;

    // Q fragments (B-operand: qrow=l31, d = ds*16+hi*8+e)
    f16x8 qf[4];
    {
        const f16* qb_ = q_h + ((size_t)bh*Lq + qW + l31)*HDq + hi*8;
        #pragma unroll
        for (int ds=0; ds<4; ++ds)
            qf[ds] = *reinterpret_cast<const f16x8*>(qb_ + ds*16);
    }

    f32x16 o0, o1;
    #pragma unroll
    for (int r=0;r<16;++r) { o0[r]=0.f; o1[r]=0.f; }
    float m_run = pos ? -1e30f : 1e30f;
    float s_run = 0.f;

    auto STAGE = [&](int t, int buf) {
        const int k0 = t*64;
        char* LK = lds + buf*16384;
        char* LV = LK + 8192;
        #pragma unroll
        for (int i=0;i<2;++i) {
            int g = tid + i*256;
            int row = g >> 3, slot = g & 7;
            int ss = slot ^ (row & 7);
            gload_lds16(kbase + (size_t)(k0+row)*HDq + ss*8, LK + g*16);
            gload_lds16(vbase + (size_t)row*Lq + k0 + ss*8,  LV + g*16);
        }
    };

    auto QMLOAD = [&](int t, f32x4 (&qm)[2][4]) {
        const char* qmb = (const char*)qm_pre
            + ((((size_t)b_*32 + t)*64 + qt)*2048)*4 + lane*16;
        #pragma unroll
        for (int kt=0;kt<2;++kt)
            #pragma unroll
            for (int j=0;j<4;++j)
                qm[kt][j] = *reinterpret_cast<const f32x4*>(qmb + kt*4096 + j*1024);
    };

    auto COMPUTE = [&](int t, int buf, f32x4 (&qmc)[2][4], f32x4 (&qmn)[2][4]) {
        const char* LK = lds + buf*16384;
        const char* LV = LK + 8192;
        // prefetch next iteration's bias fragments
        int tn = (t+1 < 32) ? t+1 : 31;
        QMLOAD(tn, qmn);

        // y = K Q^T + 8*quantum  (bias enters via accumulator init)
        f32x16 st[2];
        #pragma unroll
        for (int kt=0;kt<2;++kt)
            #pragma unroll
            for (int j=0;j<4;++j)
                #pragma unroll
                for (int c=0;c<4;++c) st[kt][4*j+c] = qmc[kt][j][c];
        __builtin_amdgcn_s_setprio(1);
        #pragma unroll
        for (int kt=0;kt<2;++kt) {
            #pragma unroll
            for (int ds=0;ds<4;++ds) {
                f16x8 ka = *reinterpret_cast<const f16x8*>(
                    LK + ((kt*32+l31)<<7) + (((ds*2+hi)^(l31&7))<<4));
                st[kt] = __builtin_amdgcn_mfma_f32_32x32x16_f16(ka, qf[ds], st[kt], 0,0,0);
            }
        }
        __builtin_amdgcn_s_setprio(0);

        // tile extremum of y (max if c1>=0 else min; block-uniform branch)
        float text;
        {
            float w_[16];
            if (pos) {
                #pragma unroll
                for (int r=0;r<16;++r) w_[r] = fmaxf(st[0][r], st[1][r]);
                #pragma unroll
                for (int w=8; w>0; w>>=1)
                    #pragma unroll
                    for (int r=0;r<w;++r) w_[r] = fmaxf(w_[r], w_[r+w]);
                text = fmaxf(w_[0], __shfl_xor(w_[0], 32));
            } else {
                #pragma unroll
                for (int r=0;r<16;++r) w_[r] = fminf(st[0][r], st[1][r]);
                #pragma unroll
                for (int w=8; w>0; w>>=1)
                    #pragma unroll
                    for (int r=0;r<w;++r) w_[r] = fminf(w_[r], w_[r+w]);
                text = fminf(w_[0], __shfl_xor(w_[0], 32));
            }
        }

        // defer-max in scaled domain: p <= 2^8
        float u = c1*(text - m_run);
        if (!__all(u <= 8.f)) {
            float m_new = pos ? fmaxf(m_run, text) : fminf(m_run, text);
            float corr = __builtin_amdgcn_exp2f(c1*(m_run - m_new));
            m_run = m_new;
            s_run *= corr;
            #pragma unroll
            for (int r=0;r<16;++r) { o0[r] *= corr; o1[r] *= corr; }
        }

        // P = 2^(c1*y - c1*m)
        float mb = c1 * m_run;
        float p[32];
        #pragma unroll
        for (int r=0;r<16;++r) {
            p[r]    = __builtin_amdgcn_exp2f(__builtin_fmaf(st[0][r], c1, -mb));
            p[16+r] = __builtin_amdgcn_exp2f(__builtin_fmaf(st[1][r], c1, -mb));
        }
        // sum tree
        float sm[16];
        #pragma unroll
        for (int r=0;r<16;++r) sm[r] = p[r] + p[r+16];
        #pragma unroll
        for (int w=8; w>0; w>>=1)
            #pragma unroll
            for (int r=0;r<w;++r) sm[r] += sm[r+w];
        s_run += sm[0];

        // pack P -> B-operand fragments
        f16x8 pb[4];
        #pragma unroll
        for (int ks=0; ks<4; ++ks) {
            int w0 = pk2(p[8*ks+0], p[8*ks+1]);
            int w1 = pk2(p[8*ks+2], p[8*ks+3]);
            int w2 = pk2(p[8*ks+4], p[8*ks+5]);
            int w3 = pk2(p[8*ks+6], p[8*ks+7]);
            swap32(w0, w2);
            swap32(w1, w3);
            union { int w[4]; f16x8 v; } u2;
            u2.w[0]=w0; u2.w[1]=w1; u2.w[2]=w2; u2.w[3]=w3;
            pb[ks] = u2.v;
        }

        // O^T += V^T P^T
        __builtin_amdgcn_s_setprio(1);
        #pragma unroll
        for (int ks=0; ks<4; ++ks) {
            f16x8 va0 = *reinterpret_cast<const f16x8*>(
                LV + (l31<<7)        + (((ks*2+hi)^(l31&7))<<4));
            f16x8 va1 = *reinterpret_cast<const f16x8*>(
                LV + ((32+l31)<<7)   + (((ks*2+hi)^(l31&7))<<4));
            o0 = __builtin_amdgcn_mfma_f32_32x32x16_f16(va0, pb[ks], o0, 0,0,0);
            o1 = __builtin_amdgcn_mfma_f32_32x32x16_f16(va1, pb[ks], o1, 0,0,0);
        }
        __builtin_amdgcn_s_setprio(0);
    };

    f32x4 qmE[2][4], qmO[2][4];

    // prologue
    QMLOAD(0, qmE);
    STAGE(0, 0);
    STAGE(1, 1);

    #define VMW(n) asm volatile("s_waitcnt vmcnt(" #n ")" ::: "memory")

    // t=0: younger than STAGE(0) = STAGE(1) -> 4
    VMW(4);  __builtin_amdgcn_s_barrier();
    STAGE(2, 2);  COMPUTE(0, 0, qmE, qmO);
    // t=1: younger than STAGE(1) = STAGE(2)+QM(1) -> 12
    VMW(12); __builtin_amdgcn_s_barrier();
    STAGE(3, 0);  COMPUTE(1, 1, qmO, qmE);
    // steady: younger than STAGE(t) = QM(t-1)+STAGE(t+1)+QM(t) -> 20
    for (int t = 2; t < 30; t += 2) {
        VMW(20); __builtin_amdgcn_s_barrier();
        STAGE(t+2, (t+2)%3); COMPUTE(t, t%3, qmE, qmO);
        VMW(20); __builtin_amdgcn_s_barrier();
        STAGE(t+3, (t+3)%3); COMPUTE(t+1, (t+1)%3, qmO, qmE);
    }
    // t=30: younger than STAGE(30) = QM(29)+STAGE(31)+QM(30) -> 20
    VMW(20); __builtin_amdgcn_s_barrier();
    COMPUTE(30, 0, qmE, qmO);
    // t=31: younger than STAGE(31) = QM(30)+QM(31) -> 16
    VMW(16); __builtin_amdgcn_s_barrier();
    COMPUTE(31, 1, qmO, qmE);

    #undef VMW

    // epilogue
    float s_tot = s_run + __shfl_xor(s_run, 32);
    float inv = 1.0f / s_tot;
    float* ob = out + ((size_t)b_*Lq + qW + l31)*Dq + h*HDq;
    #pragma unroll
    for (int r=0;r<16;++r) {
        int drow = (r&3) + 8*(r>>2) + 4*hi;
        ob[drow]      = o0[r]*inv;
        ob[32 + drow] = o1[r]*inv;
    }
}

extern "C" void kernel_launch(void* const* d_in, const int* in_sizes, int n_in,
                              void* d_out, int out_size, void* d_ws, size_t ws_size,
                              hipStream_t stream) {
    const float* x       = (const float*)d_in[0];
    const float* quantum = (const float*)d_in[1];
    const float* wq      = (const float*)d_in[2];
    const float* wk      = (const float*)d_in[3];
    const float* wv      = (const float*)d_in[4];
    const float* scale   = (const float*)d_in[5];
    float* out = (float*)d_out;

    f16* ws     = (f16*)d_ws;
    f16* x_h    = ws;
    f16* wq_h   = ws + 4194304;
    f16* wk_h   = ws + 5242880;
    f16* wv_h   = ws + 6291456;
    f16* q_h    = ws + 7340032;
    f16* k_h    = ws + 11534336;
    f16* vT_h   = ws + 15728640;
    float* qm32 = (float*)(ws + 19922944);   // 8,388,608 f32 = 33.5 MB (tot 73.4 MB)

    convert_kernel<<<1024, 256, 0, stream>>>(x, wq, wk, wv, x_h, wq_h, wk_h, wv_h);

    dim3 gq(64, 32, 2);
    qm_pre_kernel<<<gq, 256, 0, stream>>>(quantum, qm32);

    dim3 g1(Dq/GBN, (Bq*Lq)/GBM, 3);
    qkv_mfma_kernel<<<g1, 256, 0, stream>>>(x_h, wq_h, wk_h, wv_h, q_h, k_h, vT_h);

    dim3 g2(Bq*Hq, Lq/128);
    attn4_kernel<<<g2, 256, 0, stream>>>(q_h, k_h, vT_h, qm32, scale, out);
}